// Round 5
// baseline (350.351 us; speedup 1.0000x reference)
//
#include <hip/hip_runtime.h>
#include <hip/hip_cooperative_groups.h>
#include <stdint.h>

namespace cg = cooperative_groups;

#define M_NODES 4001
#define NW 63            // ceil(4001/64) words per adjacency row
#define DIM 128
#define THRESH 0.04f
#define MAXJ 384         // cap |M2(i)| (mean ~80, max ~150)
#define CAP 96           // cap degree (mean ~21)
#define MAXNPB 8         // max nodes per block (grid >= 512)

// 6-step inclusive shfl scan over 64 lanes.
__device__ __forceinline__ int wave64_incl_scan(int v, int lane) {
#pragma unroll
    for (int d = 1; d < 64; d <<= 1) {
        int n = __shfl_up(v, d, 64);
        if (lane >= d) v += n;
    }
    return v;
}

__global__ __launch_bounds__(256, 3)
void ccn_all(const float* __restrict__ node_loc, const float* __restrict__ td,
             const float* __restrict__ depot, const float* __restrict__ W0w,
             const float* __restrict__ W0b,
             uint64_t* __restrict__ A, int* __restrict__ nbr,
             int* __restrict__ deg, float* __restrict__ fv1,
             float* __restrict__ out, int npb) {
    __shared__ float2 sloc[M_NODES];       // 32,008 B — all node coords
    __shared__ float sW0[DIM * 4];         // 2 KB  — w0,w1,w2,b per dim
    __shared__ uint64_t myA[MAXNPB][64];   // 4 KB  — my adjacency rows
    __shared__ int slist[MAXNPB][CAP];     // 3 KB  — my neighbor lists
    __shared__ int sdeg[MAXNPB];
    __shared__ float tdbuf[2][CAP];        // staged deadlines for fv1 pair
    __shared__ uint64_t m2row[64];         // 512 B — M2 row (fv2)
    __shared__ int list2[MAXJ];            // 1.5 KB
    __shared__ float cnt[MAXJ];            // 1.5 KB
    __shared__ float4 part[8][32];         // 4 KB
    __shared__ int sn2;

    int tid = threadIdx.x;
    int lane = tid & 63, wave = tid >> 6;
    int node0 = blockIdx.x * npb;

    // ---- stage all coords + W0 in LDS ----
    for (int j = tid; j < M_NODES; j += 256) {
        float2 c;
        if (j == 0) { c.x = depot[0]; c.y = depot[1]; }
        else { c.x = node_loc[(j - 1) * 2]; c.y = node_loc[(j - 1) * 2 + 1]; }
        sloc[j] = c;
    }
    if (tid < DIM) {
        sW0[tid * 4 + 0] = W0w[tid * 3 + 0];
        sW0[tid * 4 + 1] = W0w[tid * 3 + 1];
        sW0[tid * 4 + 2] = W0w[tid * 3 + 2];
        sW0[tid * 4 + 3] = W0b[tid];
    }
    __syncthreads();

    // ---- adjacency rows for my nodes: wave ballot assembles 64-bit words ----
    // word w = k*4 + wave covers j in [w*64, w*64+64); predicate bit-matches
    // numpy: dx*dx + dy*dy (contract off), correctly-rounded sqrtf, <= 0.04f.
    for (int r = 0; r < npb; ++r) {
        int i = node0 + r;
        if (i >= M_NODES) break;                 // block-uniform
        float xi = sloc[i].x, yi = sloc[i].y;
#pragma unroll 4
        for (int k = 0; k < 16; ++k) {
            int j = k * 256 + tid;
            float2 cj = sloc[j < M_NODES ? j : 0];
            bool pred;
            {
#pragma clang fp contract(off)
                float dx = xi - cj.x, dy = yi - cj.y;
                float xx = dx * dx, yy = dy * dy;
                float d2 = xx + yy;
                pred = (j < M_NODES) && (sqrtf(d2) <= THRESH);
            }
            uint64_t m = __ballot(pred);
            int w = k * 4 + wave;
            if (lane == 0) {
                myA[r][w] = m;
                if (w < NW) A[(size_t)i * NW + w] = m;   // coalesced enough; 504B/row
            }
        }
    }
    __syncthreads();

    // ---- CSR per node: wave v handles node rr+v (scan + bit-walk) ----
    for (int rr = 0; rr < npb; rr += 4) {
        int r = rr + wave;
        if (r < npb) {
            int i = node0 + r;
            if (i < M_NODES) {
                uint64_t m = myA[r][lane];
                int c = __popcll(m);
                int incl = wave64_incl_scan(c, lane);
                int oo = incl - c, base = lane * 64;
                while (m) {
                    int b = __builtin_ctzll(m);
                    if (oo < CAP) { slist[r][oo] = base + b; nbr[(size_t)i * CAP + oo] = base + b; }
                    ++oo;
                    m &= m - 1;
                }
                if (lane == 63) {
                    int t = incl < CAP ? incl : CAP;
                    sdeg[r] = t;
                    deg[i] = t;
                }
            } else if (lane == 0) sdeg[r] = 0;
        }
    }
    __syncthreads();

    // ---- fv1: recompute fv0 on the fly (coords from LDS, td staged) ----
    // two nodes per round: tid>>7 selects node, tid&127 = dim.
    for (int rr = 0; rr < npb; rr += 2) {
        int which = tid / CAP;      // 0/1 stage td for the pair
        int l = tid - which * CAP;
        if (which < 2) {
            int r = rr + which;
            if (r < npb && node0 + r < M_NODES && l < sdeg[r]) {
                int j = slist[r][l];
                tdbuf[which][l] = (j == 0) ? 0.f : td[j - 1];
            }
        }
        __syncthreads();
        int half = tid >> 7, d = tid & 127;
        int r = rr + half;
        if (r < npb && node0 + r < M_NODES) {
            float w0 = sW0[d * 4 + 0], w1 = sW0[d * 4 + 1];
            float w2 = sW0[d * 4 + 2], bb = sW0[d * 4 + 3];
            int n1 = sdeg[r];
            float acc = 0.f;
            for (int l2 = 0; l2 < n1; ++l2) {
                int j = slist[r][l2];               // uniform -> broadcast
                float2 c = sloc[j];
                float v = fmaf(c.x, w0, fmaf(c.y, w1, fmaf(tdbuf[half][l2], w2, bb)));
                acc += v > 0.f ? v : 0.f;
            }
            fv1[(size_t)(node0 + r) * DIM + d] = acc;   // coalesced 512B
        }
        __syncthreads();
    }

    __threadfence();
    cg::this_grid().sync();

    // ---- fv2: per my-node, M2 row -> counts -> weighted sum ----
    for (int r = 0; r < npb; ++r) {
        int i = node0 + r;
        if (i >= M_NODES) break;                 // block-uniform
        int n1 = sdeg[r];
        if (wave == 0) m2row[lane] = 0ull;
        __syncthreads();
        for (int l = wave; l < n1; l += 4) {
            int j = slist[r][l];
            if (lane < NW) {
                uint64_t aj = A[(size_t)j * NW + lane];     // coalesced 504B
                if (aj) atomicOr((unsigned long long*)&m2row[lane], (unsigned long long)aj);
            }
        }
        __syncthreads();
        // wave 0: scan + deterministic enumerate of M2(i)
        if (wave == 0) {
            uint64_t m = m2row[lane];
            int c = __popcll(m);
            int incl = wave64_incl_scan(c, lane);
            int oo = incl - c, base = lane * 64;
            while (m) {
                int b = __builtin_ctzll(m);
                if (oo < MAXJ) list2[oo] = base + b;
                ++oo;
                m &= m - 1;
            }
            if (lane == 63) sn2 = incl < MAXJ ? incl : MAXJ;
        }
        __syncthreads();
        int n2 = sn2;
        // counts: one wave per j; c_j = |M2(i) ∩ N(j)| via ballot+popcount
        for (int l = wave; l < n2; l += 4) {
            int j = list2[l];
            int dj = deg[j];                      // same addr -> broadcast
            int c = 0;
            for (int k0 = 0; k0 < dj; k0 += 64) { // dj<=64 in practice: 1 iter
                int kk = k0 + lane;
                bool pred = false;
                if (kk < dj) {
                    int u = nbr[(size_t)j * CAP + kk];   // coalesced
                    pred = (m2row[u >> 6] >> (u & 63)) & 1ull;
                }
                c += (int)__popcll(__ballot(pred));
            }
            if (lane == 0) cnt[l] = (float)c;     // exact small int
        }
        __syncthreads();
        // weighted sum of fv1 rows: 8 groups x 32 lanes x float4
        int lane32 = tid & 31, g = tid >> 5;
        const float4* fv1v = (const float4*)fv1;
        float4 acc = {0.f, 0.f, 0.f, 0.f};
        for (int l = g; l < n2; l += 8) {
            float c0 = cnt[l];
            float4 v = fv1v[(size_t)list2[l] * 32 + lane32];
            acc.x = fmaf(c0, v.x, acc.x); acc.y = fmaf(c0, v.y, acc.y);
            acc.z = fmaf(c0, v.z, acc.z); acc.w = fmaf(c0, v.w, acc.w);
        }
        part[g][lane32] = acc;
        __syncthreads();
        if (tid < 32) {
            float4 s = part[0][tid];
#pragma unroll
            for (int gg = 1; gg < 8; ++gg) {
                float4 p = part[gg][tid];
                s.x += p.x; s.y += p.y; s.z += p.z; s.w += p.w;
            }
            ((float4*)out)[(size_t)i * 32 + tid] = s;
        }
        __syncthreads();
    }
}

extern "C" void kernel_launch(void* const* d_in, const int* in_sizes, int n_in,
                              void* d_out, int out_size, void* d_ws, size_t ws_size,
                              hipStream_t stream) {
    const float* node_loc = (const float*)d_in[0];  // [4000,2]
    const float* td       = (const float*)d_in[1];  // [4000,1]
    const float* depot    = (const float*)d_in[2];  // [1,2]
    const float* W0w      = (const float*)d_in[3];  // [128,3]
    const float* W0b      = (const float*)d_in[4];  // [128]
    float* out = (float*)d_out;                     // [4001,128]

    char* base = (char*)d_ws;
    size_t off = 0;
    auto carve = [&](size_t bytes) {
        char* p = base + off;
        off = (off + bytes + 511) & ~(size_t)511;
        return p;
    };
    uint64_t* A   = (uint64_t*)carve((size_t)M_NODES * NW * sizeof(uint64_t));  // ~2.0 MB
    int*      nbr = (int*)     carve((size_t)M_NODES * CAP * sizeof(int));      // ~1.5 MB
    int*      deg = (int*)     carve((size_t)M_NODES * sizeof(int));            // 16 KB
    float*    fv1 = (float*)   carve((size_t)M_NODES * DIM * sizeof(float));    // ~2.0 MB

    // Guaranteed-co-resident cooperative grid: 3 blocks/CU by LDS (~50KB) and
    // __launch_bounds__(256,3); query to be safe, clamp to [2,3].
    int bpc = 0;
    hipOccupancyMaxActiveBlocksPerMultiprocessor(&bpc, ccn_all, 256, 0);
    if (bpc < 2) bpc = 2;
    if (bpc > 3) bpc = 3;
    int grid = 256 * bpc;                       // 256 CUs on MI355X
    int npb = (M_NODES + grid - 1) / grid;      // 6 (bpc=3) or 8 (bpc=2)

    void* args[] = {(void*)&node_loc, (void*)&td, (void*)&depot, (void*)&W0w,
                    (void*)&W0b, (void*)&A, (void*)&nbr, (void*)&deg,
                    (void*)&fv1, (void*)&out, (void*)&npb};
    hipLaunchCooperativeKernel((const void*)ccn_all, dim3(grid), dim3(256),
                               args, 0, stream);
}

// Round 6
// 112.286 us; speedup vs baseline: 3.1202x; 3.1202x over previous
//
#include <hip/hip_runtime.h>
#include <stdint.h>

#define M_NODES 4001
#define NW 63            // ceil(4001/64) bitmask words per row
#define DIM 128
#define THRESH 0.04f
#define MAXJ 512         // cap on |M2(i)| (mean ~80)
#define CAP 96           // cap on degree (mean ~21, Poisson tail negligible)
#define SENTINEL 4095    // bit 4095 is always 0 in m2row

// ---------- adjacency bitmask rows ----------
// blockIdx.x = 256-row group, blockIdx.y = word w. LDS candidate tile,
// wave-uniform broadcast reads. Predicate bit-matches numpy:
// d2 = dx*dx + dy*dy (contraction off), correctly-rounded sqrtf, <= 0.04f.
__global__ void adj_kernel(const float* __restrict__ node_loc,
                           const float* __restrict__ depot,
                           uint64_t* __restrict__ A) {
    __shared__ float2 cand[64];
    int w = blockIdx.y;
    int tid = threadIdx.x;
    if (tid < 64) {
        int j = w * 64 + tid;
        float2 c;
        if (j == 0) { c.x = depot[0]; c.y = depot[1]; }
        else if (j < M_NODES) { c.x = node_loc[(j - 1) * 2]; c.y = node_loc[(j - 1) * 2 + 1]; }
        else { c.x = 1e9f; c.y = 1e9f; }
        cand[tid] = c;
    }
    int i = blockIdx.x * blockDim.x + tid;
    float xi = 0.f, yi = 0.f;
    if (i == 0) { xi = depot[0]; yi = depot[1]; }
    else if (i < M_NODES) { xi = node_loc[(i - 1) * 2]; yi = node_loc[(i - 1) * 2 + 1]; }
    __syncthreads();
    uint64_t m = 0;
#pragma unroll
    for (int b = 0; b < 64; ++b) {
#pragma clang fp contract(off)
        float dx = xi - cand[b].x;
        float dy = yi - cand[b].y;
        float xx = dx * dx;
        float yy = dy * dy;
        float d2 = xx + yy;
        if (sqrtf(d2) <= THRESH) m |= (1ull << b);
    }
    if (i < M_NODES) A[(size_t)i * NW + w] = m;
}

// 6-step inclusive shfl scan over 64 lanes.
__device__ __forceinline__ int wave64_incl_scan(int v, int lane) {
#pragma unroll
    for (int d = 1; d < 64; d <<= 1) {
        int n = __shfl_up(v, d, 64);
        if (lane >= d) v += n;
    }
    return v;
}

// ---------- fused CSR build + fv_1 (fv0 recomputed inline) ----------
// wave 0: scan A row -> deterministic neighbor list (LDS + global, sentinel-
// padded to 64). Then stage neighbor feats (x,y,td) in LDS and compute
// fv1[i][d] = sum_j relu(feat_j . W0[d] + b[d]) with 8 groups x 32 x float4.
__global__ void fv1csr_kernel(const uint64_t* __restrict__ A,
                              const float* __restrict__ node_loc,
                              const float* __restrict__ td,
                              const float* __restrict__ depot,
                              const float* __restrict__ W0w,
                              const float* __restrict__ W0b,
                              int* __restrict__ nbr, int* __restrict__ deg,
                              float* __restrict__ fv1) {
    __shared__ int slist[CAP];
    __shared__ float4 sfeat[CAP];
    __shared__ float4 part[8][32];
    __shared__ int snn;
    int i = blockIdx.x, tid = threadIdx.x;
    if (tid < 64) {
        uint64_t m = (tid < NW) ? A[(size_t)i * NW + tid] : 0ull;
        int c = __popcll(m);
        int incl = wave64_incl_scan(c, tid);
        int oo = incl - c;
        int base = tid * 64;
        while (m) {
            int b = __builtin_ctzll(m);
            if (oo < CAP) { slist[oo] = base + b; nbr[(size_t)i * CAP + oo] = base + b; }
            ++oo;
            m &= m - 1;
        }
        int tot = __shfl(incl, 63, 64);
        if (tot > CAP) tot = CAP;
        if (tid == 0) { deg[i] = tot; snn = tot; }
        int s = tot + tid;                       // sentinel-pad slots [tot,64)
        if (s < 64) nbr[(size_t)i * CAP + s] = SENTINEL;
    }
    __syncthreads();
    int n1 = snn;
    if (tid < n1) {
        int j = slist[tid];
        float4 f;
        if (j == 0) { f.x = depot[0]; f.y = depot[1]; f.z = 0.f; }
        else { f.x = node_loc[(j - 1) * 2]; f.y = node_loc[(j - 1) * 2 + 1]; f.z = td[j - 1]; }
        f.w = 0.f;
        sfeat[tid] = f;
    }
    __syncthreads();
    int lane32 = tid & 31, g = tid >> 5;
    int d0 = lane32 * 4;
    // per-thread W0 rows d0..d0+3 (L1/L2-resident, same 2KB for all blocks)
    float wx0 = W0w[(d0 + 0) * 3], wy0 = W0w[(d0 + 0) * 3 + 1], wz0 = W0w[(d0 + 0) * 3 + 2], b0 = W0b[d0 + 0];
    float wx1 = W0w[(d0 + 1) * 3], wy1 = W0w[(d0 + 1) * 3 + 1], wz1 = W0w[(d0 + 1) * 3 + 2], b1 = W0b[d0 + 1];
    float wx2 = W0w[(d0 + 2) * 3], wy2 = W0w[(d0 + 2) * 3 + 1], wz2 = W0w[(d0 + 2) * 3 + 2], b2 = W0b[d0 + 2];
    float wx3 = W0w[(d0 + 3) * 3], wy3 = W0w[(d0 + 3) * 3 + 1], wz3 = W0w[(d0 + 3) * 3 + 2], b3 = W0b[d0 + 3];
    float4 acc = {0.f, 0.f, 0.f, 0.f};
    for (int l = g; l < n1; l += 8) {
        float4 f = sfeat[l];                       // 2 distinct addrs per wave
        float v0 = fmaf(f.x, wx0, fmaf(f.y, wy0, fmaf(f.z, wz0, b0)));
        float v1 = fmaf(f.x, wx1, fmaf(f.y, wy1, fmaf(f.z, wz1, b1)));
        float v2 = fmaf(f.x, wx2, fmaf(f.y, wy2, fmaf(f.z, wz2, b2)));
        float v3 = fmaf(f.x, wx3, fmaf(f.y, wy3, fmaf(f.z, wz3, b3)));
        acc.x += fmaxf(v0, 0.f); acc.y += fmaxf(v1, 0.f);
        acc.z += fmaxf(v2, 0.f); acc.w += fmaxf(v3, 0.f);
    }
    part[g][lane32] = acc;
    __syncthreads();
    if (tid < 32) {
        float4 s = part[0][tid];
#pragma unroll
        for (int gg = 1; gg < 8; ++gg) {
            float4 p = part[gg][tid];
            s.x += p.x; s.y += p.y; s.z += p.z; s.w += p.w;
        }
        ((float4*)fv1)[(size_t)i * 32 + tid] = s;
    }
}

// ---------- fv_2 ----------
// fv2[i] = sum_{j in M2(i)} |M2(i) ∩ N(j)| * fv1[j]; M2 row built in-block;
// counts via one-wave-per-j ballot over sentinel-padded nbr rows (coalesced).
__global__ void fv2_kernel(const uint64_t* __restrict__ A,
                           const int* __restrict__ nbr, const int* __restrict__ deg,
                           const float* __restrict__ fv1, float* __restrict__ out) {
    __shared__ uint64_t m2part[4][64];
    __shared__ uint64_t m2row[64];
    __shared__ int list1[CAP];
    __shared__ int list2[MAXJ];
    __shared__ float cnt[MAXJ];
    __shared__ float4 part[8][32];
    __shared__ int snn2;

    int i = blockIdx.x, tid = threadIdx.x;
    int lane = tid & 63, wave = tid >> 6;
    int n1 = deg[i];
    if (tid < CAP) list1[tid] = (tid < n1) ? nbr[(size_t)i * CAP + tid] : 0;
    __syncthreads();

    // M2 row i = OR over j in N(i) of A row j (coalesced 504B rows).
    uint64_t o = 0;
    for (int l = wave; l < n1; l += 4)
        o |= (lane < NW) ? A[(size_t)list1[l] * NW + lane] : 0ull;
    m2part[wave][lane] = o;
    __syncthreads();

    // wave 0: OR-combine, shfl-scan, deterministic enumerate of M2(i)
    if (tid < 64) {
        uint64_t m = m2part[0][tid] | m2part[1][tid] | m2part[2][tid] | m2part[3][tid];
        m2row[tid] = m;
        int c = __popcll(m);
        int incl = wave64_incl_scan(c, tid);
        int oo = incl - c;
        int base = tid * 64;
        while (m) {
            int b = __builtin_ctzll(m);
            if (oo < MAXJ) list2[oo] = base + b;
            ++oo;
            m &= m - 1;
        }
        if (tid == 63) snn2 = incl < MAXJ ? incl : MAXJ;
    }
    __syncthreads();
    int n2 = snn2;

    // counts: wave per j; c_j = |M2(i) ∩ N(j)| via coalesced nbr row + ballot.
    for (int l = wave; l < n2; l += 4) {
        int j = list2[l];                          // LDS broadcast
        int u = nbr[(size_t)j * CAP + lane];       // coalesced 256B; sentinel->bit 0
        bool pred = (m2row[u >> 6] >> (u & 63)) & 1ull;
        uint64_t bal = __ballot(pred);
        if (lane == 0) cnt[l] = (float)__popcll(bal);   // exact small int
    }
    __syncthreads();

    // weighted sum of fv1 rows: 8 groups x 32 lanes x float4
    int lane32 = tid & 31, g = tid >> 5;
    const float4* fv1v = (const float4*)fv1;
    float4 acc = {0.f, 0.f, 0.f, 0.f};
    for (int l = g; l < n2; l += 8) {
        float c0 = cnt[l];
        float4 v = fv1v[(size_t)list2[l] * 32 + lane32];
        acc.x = fmaf(c0, v.x, acc.x); acc.y = fmaf(c0, v.y, acc.y);
        acc.z = fmaf(c0, v.z, acc.z); acc.w = fmaf(c0, v.w, acc.w);
    }
    part[g][lane32] = acc;
    __syncthreads();
    if (tid < 32) {
        float4 s = part[0][tid];
#pragma unroll
        for (int gg = 1; gg < 8; ++gg) {
            float4 p = part[gg][tid];
            s.x += p.x; s.y += p.y; s.z += p.z; s.w += p.w;
        }
        ((float4*)out)[(size_t)i * 32 + tid] = s;
    }
}

extern "C" void kernel_launch(void* const* d_in, const int* in_sizes, int n_in,
                              void* d_out, int out_size, void* d_ws, size_t ws_size,
                              hipStream_t stream) {
    const float* node_loc = (const float*)d_in[0];  // [4000,2]
    const float* td       = (const float*)d_in[1];  // [4000,1]
    const float* depot    = (const float*)d_in[2];  // [1,2]
    const float* W0w      = (const float*)d_in[3];  // [128,3]
    const float* W0b      = (const float*)d_in[4];  // [128]
    float* out = (float*)d_out;                     // [4001,128]

    char* base = (char*)d_ws;
    size_t off = 0;
    auto carve = [&](size_t bytes) {
        char* p = base + off;
        off = (off + bytes + 511) & ~(size_t)511;
        return p;
    };
    uint64_t* A   = (uint64_t*)carve((size_t)M_NODES * NW * sizeof(uint64_t));  // ~2.0 MB
    float*    fv1 = (float*)   carve((size_t)M_NODES * DIM * sizeof(float));    // ~2.0 MB
    int*      nbr = (int*)     carve((size_t)M_NODES * CAP * sizeof(int));      // ~1.5 MB
    int*      deg = (int*)     carve((size_t)M_NODES * sizeof(int));            // 16 KB

    dim3 agrid((M_NODES + 255) / 256, NW);
    adj_kernel<<<agrid, 256, 0, stream>>>(node_loc, depot, A);
    fv1csr_kernel<<<M_NODES, 256, 0, stream>>>(A, node_loc, td, depot, W0w, W0b,
                                               nbr, deg, fv1);
    fv2_kernel<<<M_NODES, 256, 0, stream>>>(A, nbr, deg, fv1, out);
}

// Round 7
// 101.086 us; speedup vs baseline: 3.4659x; 1.1108x over previous
//
#include <hip/hip_runtime.h>
#include <stdint.h>

#define M_NODES 4001
#define NW 63            // ceil(4001/64) bitmask words per row
#define DIM 128
#define THRESH 0.04f
#define MAXJ 512         // cap on |M2(i)| (mean ~80)
#define CAP 96           // cap on degree (mean ~21, Poisson tail negligible)
#define SENTINEL 4095    // bit 4095 is never set in m2row (word 63 == 0)

// ---------- fv_0 = relu([loc, td] @ W0^T + b), flat over (node, dim) ----------
__global__ void fv0_kernel(const float* __restrict__ node_loc,
                           const float* __restrict__ td,
                           const float* __restrict__ depot,
                           const float* __restrict__ W0w,
                           const float* __restrict__ W0b,
                           float* __restrict__ fv0) {
    int idx = blockIdx.x * blockDim.x + threadIdx.x;
    if (idx >= M_NODES * DIM) return;
    int i = idx >> 7;
    int d = idx & (DIM - 1);
    float lx, ly, t;
    if (i == 0) { lx = depot[0]; ly = depot[1]; t = 0.f; }
    else { lx = node_loc[(i - 1) * 2]; ly = node_loc[(i - 1) * 2 + 1]; t = td[i - 1]; }
    float v = fmaf(lx, W0w[d * 3 + 0], fmaf(ly, W0w[d * 3 + 1], fmaf(t, W0w[d * 3 + 2], W0b[d])));
    fv0[idx] = v > 0.f ? v : 0.f;
}

// ---------- adjacency bitmask rows ----------
// blockIdx.x = 256-row group, blockIdx.y = word w. LDS candidate tile,
// wave-uniform broadcast reads. Predicate bit-matches numpy:
// d2 = dx*dx + dy*dy (contraction off), correctly-rounded sqrtf, <= 0.04f.
__global__ void adj_kernel(const float* __restrict__ node_loc,
                           const float* __restrict__ depot,
                           uint64_t* __restrict__ A) {
    __shared__ float2 cand[64];
    int w = blockIdx.y;
    int tid = threadIdx.x;
    if (tid < 64) {
        int j = w * 64 + tid;
        float2 c;
        if (j == 0) { c.x = depot[0]; c.y = depot[1]; }
        else if (j < M_NODES) { c.x = node_loc[(j - 1) * 2]; c.y = node_loc[(j - 1) * 2 + 1]; }
        else { c.x = 1e9f; c.y = 1e9f; }
        cand[tid] = c;
    }
    int i = blockIdx.x * blockDim.x + tid;
    float xi = 0.f, yi = 0.f;
    if (i == 0) { xi = depot[0]; yi = depot[1]; }
    else if (i < M_NODES) { xi = node_loc[(i - 1) * 2]; yi = node_loc[(i - 1) * 2 + 1]; }
    __syncthreads();
    uint64_t m = 0;
#pragma unroll
    for (int b = 0; b < 64; ++b) {
#pragma clang fp contract(off)
        float dx = xi - cand[b].x;
        float dy = yi - cand[b].y;
        float xx = dx * dx;
        float yy = dy * dy;
        float d2 = xx + yy;
        if (sqrtf(d2) <= THRESH) m |= (1ull << b);
    }
    if (i < M_NODES) A[(size_t)i * NW + w] = m;
}

// 6-step inclusive shfl scan over 64 lanes.
__device__ __forceinline__ int wave64_incl_scan(int v, int lane) {
#pragma unroll
    for (int d = 1; d < 64; d <<= 1) {
        int n = __shfl_up(v, d, 64);
        if (lane >= d) v += n;
    }
    return v;
}

// ---------- fused CSR build + fv_1 ----------
// wave 0: scan A row -> deterministic neighbor list (LDS + global nbr, sentinel-
// padded to 64 entries). All 256 threads: fv1[i] = sum_j fv0[j],
// 8 groups x 32 lanes x float4 over coalesced fv0 rows.
__global__ void fv1csr_kernel(const uint64_t* __restrict__ A,
                              const float* __restrict__ fv0,
                              int* __restrict__ nbr, int* __restrict__ deg,
                              float* __restrict__ fv1) {
    __shared__ int slist[CAP];
    __shared__ float4 part[8][32];
    __shared__ int snn;
    int i = blockIdx.x, tid = threadIdx.x;
    if (tid < 64) {
        uint64_t m = (tid < NW) ? A[(size_t)i * NW + tid] : 0ull;
        int c = __popcll(m);
        int incl = wave64_incl_scan(c, tid);
        int oo = incl - c;
        int base = tid * 64;
        while (m) {
            int b = __builtin_ctzll(m);
            if (oo < CAP) { slist[oo] = base + b; nbr[(size_t)i * CAP + oo] = base + b; }
            ++oo;
            m &= m - 1;
        }
        int tot = __shfl(incl, 63, 64);
        if (tot > CAP) tot = CAP;
        if (tid == 0) { deg[i] = tot; snn = tot; }
        int s = tot + tid;                       // sentinel-pad slots [tot,64)
        if (s < 64) nbr[(size_t)i * CAP + s] = SENTINEL;
    }
    __syncthreads();
    int n1 = snn;
    int lane32 = tid & 31, g = tid >> 5;
    const float4* fv0v = (const float4*)fv0;     // row = 32 float4
    float4 acc = {0.f, 0.f, 0.f, 0.f};
    for (int l = g; l < n1; l += 8) {
        float4 v = fv0v[(size_t)slist[l] * 32 + lane32];
        acc.x += v.x; acc.y += v.y; acc.z += v.z; acc.w += v.w;
    }
    part[g][lane32] = acc;
    __syncthreads();
    if (tid < 32) {
        float4 s = part[0][tid];
#pragma unroll
        for (int gg = 1; gg < 8; ++gg) {
            float4 p = part[gg][tid];
            s.x += p.x; s.y += p.y; s.z += p.z; s.w += p.w;
        }
        ((float4*)fv1)[(size_t)i * 32 + tid] = s;
    }
}

// ---------- fv_2 ----------
// fv2[i] = sum_{j in M2(i)} |M2(i) ∩ N(j)| * fv1[j].
// M2 row built in-block (unroll-2 OR of neighbor A-rows); counts and weighted
// sum FUSED: per wave-round, one coalesced nbr row (256B) -> ballot popcount,
// one coalesced fv1 row (512B float2) -> FMA. Unroll-2 => 4 loads in flight.
__global__ void fv2_kernel(const uint64_t* __restrict__ A,
                           const int* __restrict__ nbr, const int* __restrict__ deg,
                           const float* __restrict__ fv1, float* __restrict__ out) {
    __shared__ uint64_t m2part[4][64];
    __shared__ uint64_t m2row[64];
    __shared__ int list1[CAP];
    __shared__ int list2[MAXJ];
    __shared__ float2 wacc[3][64];
    __shared__ int snn2;

    int i = blockIdx.x, tid = threadIdx.x;
    int lane = tid & 63, wave = tid >> 6;
    int n1 = deg[i];
    if (tid < CAP) list1[tid] = (tid < n1) ? nbr[(size_t)i * CAP + tid] : 0;
    __syncthreads();

    // M2 row i = OR over j in N(i) of A row j (coalesced 504B rows), unroll-2.
    uint64_t o = 0;
    {
        int l = wave;
        for (; l + 4 < n1; l += 8) {
            uint64_t a0 = (lane < NW) ? A[(size_t)list1[l] * NW + lane] : 0ull;
            uint64_t a1 = (lane < NW) ? A[(size_t)list1[l + 4] * NW + lane] : 0ull;
            o |= a0 | a1;
        }
        if (l < n1) o |= (lane < NW) ? A[(size_t)list1[l] * NW + lane] : 0ull;
    }
    m2part[wave][lane] = o;
    __syncthreads();

    // wave 0: OR-combine, shfl-scan, deterministic enumerate of M2(i)
    if (tid < 64) {
        uint64_t m = m2part[0][tid] | m2part[1][tid] | m2part[2][tid] | m2part[3][tid];
        m2row[tid] = m;
        int c = __popcll(m);
        int incl = wave64_incl_scan(c, tid);
        int oo = incl - c;
        int base = tid * 64;
        while (m) {
            int b = __builtin_ctzll(m);
            if (oo < MAXJ) list2[oo] = base + b;
            ++oo;
            m &= m - 1;
        }
        if (tid == 63) snn2 = incl < MAXJ ? incl : MAXJ;
    }
    __syncthreads();
    int n2 = snn2;

    // fused counts + weighted sum: wave per j, unroll-2.
    const float2* fv1v = (const float2*)fv1;     // row = 64 float2
    float2 acc = {0.f, 0.f};
    {
        int l = wave;
        for (; l + 4 < n2; l += 8) {
            int j0 = list2[l];                   // LDS broadcast
            int j1 = list2[l + 4];
            int u0 = nbr[(size_t)j0 * CAP + lane];       // coalesced 256B
            int u1 = nbr[(size_t)j1 * CAP + lane];
            float2 r0 = fv1v[(size_t)j0 * 64 + lane];    // coalesced 512B
            float2 r1 = fv1v[(size_t)j1 * 64 + lane];
            bool p0 = (m2row[u0 >> 6] >> (u0 & 63)) & 1ull;
            bool p1 = (m2row[u1 >> 6] >> (u1 & 63)) & 1ull;
            float c0 = (float)__popcll(__ballot(p0));    // exact small int
            float c1 = (float)__popcll(__ballot(p1));
            acc.x = fmaf(c0, r0.x, acc.x); acc.y = fmaf(c0, r0.y, acc.y);
            acc.x = fmaf(c1, r1.x, acc.x); acc.y = fmaf(c1, r1.y, acc.y);
        }
        if (l < n2) {
            int j0 = list2[l];
            int u0 = nbr[(size_t)j0 * CAP + lane];
            float2 r0 = fv1v[(size_t)j0 * 64 + lane];
            bool p0 = (m2row[u0 >> 6] >> (u0 & 63)) & 1ull;
            float c0 = (float)__popcll(__ballot(p0));
            acc.x = fmaf(c0, r0.x, acc.x); acc.y = fmaf(c0, r0.y, acc.y);
        }
    }
    if (wave > 0) wacc[wave - 1][lane] = acc;
    __syncthreads();
    if (wave == 0) {
        float2 s0 = wacc[0][lane], s1 = wacc[1][lane], s2 = wacc[2][lane];
        float2 s = { acc.x + s0.x + s1.x + s2.x, acc.y + s0.y + s1.y + s2.y };
        ((float2*)out)[(size_t)i * 64 + lane] = s;   // coalesced 512B
    }
}

extern "C" void kernel_launch(void* const* d_in, const int* in_sizes, int n_in,
                              void* d_out, int out_size, void* d_ws, size_t ws_size,
                              hipStream_t stream) {
    const float* node_loc = (const float*)d_in[0];  // [4000,2]
    const float* td       = (const float*)d_in[1];  // [4000,1]
    const float* depot    = (const float*)d_in[2];  // [1,2]
    const float* W0w      = (const float*)d_in[3];  // [128,3]
    const float* W0b      = (const float*)d_in[4];  // [128]
    float* out = (float*)d_out;                     // [4001,128]

    char* base = (char*)d_ws;
    size_t off = 0;
    auto carve = [&](size_t bytes) {
        char* p = base + off;
        off = (off + bytes + 511) & ~(size_t)511;
        return p;
    };
    uint64_t* A   = (uint64_t*)carve((size_t)M_NODES * NW * sizeof(uint64_t));  // ~2.0 MB
    float*    fv0 = (float*)   carve((size_t)M_NODES * DIM * sizeof(float));    // ~2.0 MB
    float*    fv1 = (float*)   carve((size_t)M_NODES * DIM * sizeof(float));    // ~2.0 MB
    int*      nbr = (int*)     carve((size_t)M_NODES * CAP * sizeof(int));      // ~1.5 MB
    int*      deg = (int*)     carve((size_t)M_NODES * sizeof(int));            // 16 KB

    fv0_kernel<<<(M_NODES * DIM + 255) / 256, 256, 0, stream>>>(node_loc, td, depot, W0w, W0b, fv0);
    dim3 agrid((M_NODES + 255) / 256, NW);
    adj_kernel<<<agrid, 256, 0, stream>>>(node_loc, depot, A);
    fv1csr_kernel<<<M_NODES, 256, 0, stream>>>(A, fv0, nbr, deg, fv1);
    fv2_kernel<<<M_NODES, 256, 0, stream>>>(A, nbr, deg, fv1, out);
}

// Round 8
// 100.331 us; speedup vs baseline: 3.4920x; 1.0075x over previous
//
#include <hip/hip_runtime.h>
#include <stdint.h>

#define M_NODES 4001
#define NW 63            // ceil(4001/64) bitmask words per row
#define DIM 128
#define THRESH 0.04f
#define MAXJ 512         // cap on |M2(i)| (mean ~80)
#define CAP 96           // cap on degree (mean ~21, Poisson tail negligible)
#define SENTINEL 4095    // bit 4095 is never set in m2row (word 63 == 0)
#define ADJ_RG 16        // row-groups of 256 rows
#define ADJ_BLOCKS (ADJ_RG * NW)   // 1008
#define FV0_BLOCKS ((M_NODES * DIM + 255) / 256)  // 2001

// ---------- fused fv0 + adjacency ----------
// blocks [0, ADJ_BLOCKS): adjacency bitmask tile (row-group rg, word w).
// blocks [ADJ_BLOCKS, ...): fv0 = relu([loc,td] @ W0^T + b), flat elementwise.
// Adjacency predicate bit-matches numpy: d2 = dx*dx + dy*dy (contraction off),
// correctly-rounded sqrtf, <= 0.04f.
__global__ void prep_kernel(const float* __restrict__ node_loc,
                            const float* __restrict__ td,
                            const float* __restrict__ depot,
                            const float* __restrict__ W0w,
                            const float* __restrict__ W0b,
                            uint64_t* __restrict__ A,
                            float* __restrict__ fv0) {
    int tid = threadIdx.x;
    if (blockIdx.x < ADJ_BLOCKS) {
        __shared__ float2 cand[64];
        int rg = blockIdx.x & (ADJ_RG - 1);
        int w  = blockIdx.x >> 4;          // 0..62
        if (tid < 64) {
            int j = w * 64 + tid;
            float2 c;
            if (j == 0) { c.x = depot[0]; c.y = depot[1]; }
            else if (j < M_NODES) { c.x = node_loc[(j - 1) * 2]; c.y = node_loc[(j - 1) * 2 + 1]; }
            else { c.x = 1e9f; c.y = 1e9f; }
            cand[tid] = c;
        }
        int i = rg * 256 + tid;
        float xi = 0.f, yi = 0.f;
        if (i == 0) { xi = depot[0]; yi = depot[1]; }
        else if (i < M_NODES) { xi = node_loc[(i - 1) * 2]; yi = node_loc[(i - 1) * 2 + 1]; }
        __syncthreads();
        uint64_t m = 0;
#pragma unroll
        for (int b = 0; b < 64; ++b) {
#pragma clang fp contract(off)
            float dx = xi - cand[b].x;
            float dy = yi - cand[b].y;
            float xx = dx * dx;
            float yy = dy * dy;
            float d2 = xx + yy;
            if (sqrtf(d2) <= THRESH) m |= (1ull << b);
        }
        if (i < M_NODES) A[(size_t)i * NW + w] = m;
    } else {
        int idx = (blockIdx.x - ADJ_BLOCKS) * 256 + tid;
        if (idx >= M_NODES * DIM) return;
        int i = idx >> 7;
        int d = idx & (DIM - 1);
        float lx, ly, t;
        if (i == 0) { lx = depot[0]; ly = depot[1]; t = 0.f; }
        else { lx = node_loc[(i - 1) * 2]; ly = node_loc[(i - 1) * 2 + 1]; t = td[i - 1]; }
        float v = fmaf(lx, W0w[d * 3 + 0], fmaf(ly, W0w[d * 3 + 1], fmaf(t, W0w[d * 3 + 2], W0b[d])));
        fv0[idx] = v > 0.f ? v : 0.f;
    }
}

// 6-step inclusive shfl scan over 64 lanes.
__device__ __forceinline__ int wave64_incl_scan(int v, int lane) {
#pragma unroll
    for (int d = 1; d < 64; d <<= 1) {
        int n = __shfl_up(v, d, 64);
        if (lane >= d) v += n;
    }
    return v;
}

// ---------- fused CSR build + fv_1 ----------
// wave 0: scan A row -> deterministic neighbor list (LDS + global nbr, sentinel-
// padded to 64 entries). All 256 threads: fv1[i] = sum_j fv0[j],
// 8 groups x 32 lanes x float4 over coalesced fv0 rows.
__global__ void fv1csr_kernel(const uint64_t* __restrict__ A,
                              const float* __restrict__ fv0,
                              int* __restrict__ nbr, int* __restrict__ deg,
                              float* __restrict__ fv1) {
    __shared__ int slist[CAP];
    __shared__ float4 part[8][32];
    __shared__ int snn;
    int i = blockIdx.x, tid = threadIdx.x;
    if (tid < 64) {
        uint64_t m = (tid < NW) ? A[(size_t)i * NW + tid] : 0ull;
        int c = __popcll(m);
        int incl = wave64_incl_scan(c, tid);
        int oo = incl - c;
        int base = tid * 64;
        while (m) {
            int b = __builtin_ctzll(m);
            if (oo < CAP) { slist[oo] = base + b; nbr[(size_t)i * CAP + oo] = base + b; }
            ++oo;
            m &= m - 1;
        }
        int tot = __shfl(incl, 63, 64);
        if (tot > CAP) tot = CAP;
        if (tid == 0) { deg[i] = tot; snn = tot; }
        int s = tot + tid;                       // sentinel-pad slots [tot,64)
        if (s < 64) nbr[(size_t)i * CAP + s] = SENTINEL;
    }
    __syncthreads();
    int n1 = snn;
    int lane32 = tid & 31, g = tid >> 5;
    const float4* fv0v = (const float4*)fv0;     // row = 32 float4
    float4 acc = {0.f, 0.f, 0.f, 0.f};
    for (int l = g; l < n1; l += 8) {
        float4 v = fv0v[(size_t)slist[l] * 32 + lane32];
        acc.x += v.x; acc.y += v.y; acc.z += v.z; acc.w += v.w;
    }
    part[g][lane32] = acc;
    __syncthreads();
    if (tid < 32) {
        float4 s = part[0][tid];
#pragma unroll
        for (int gg = 1; gg < 8; ++gg) {
            float4 p = part[gg][tid];
            s.x += p.x; s.y += p.y; s.z += p.z; s.w += p.w;
        }
        ((float4*)fv1)[(size_t)i * 32 + tid] = s;
    }
}

// ---------- fv_2 ----------
// fv2[i] = sum_{j in M2(i)} |M2(i) ∩ N(j)| * fv1[j].
// M2 row built in-block (unroll-2 OR of neighbor A-rows); counts and weighted
// sum fused, wave-per-j, UNROLL-4: 8 independent loads in flight per round.
__global__ void fv2_kernel(const uint64_t* __restrict__ A,
                           const int* __restrict__ nbr, const int* __restrict__ deg,
                           const float* __restrict__ fv1, float* __restrict__ out) {
    __shared__ uint64_t m2part[4][64];
    __shared__ uint64_t m2row[64];
    __shared__ int list1[CAP];
    __shared__ int list2[MAXJ];
    __shared__ float2 wacc[3][64];
    __shared__ int snn2;

    int i = blockIdx.x, tid = threadIdx.x;
    int lane = tid & 63, wave = tid >> 6;
    int n1 = deg[i];
    if (tid < CAP) list1[tid] = (tid < n1) ? nbr[(size_t)i * CAP + tid] : 0;
    __syncthreads();

    // M2 row i = OR over j in N(i) of A row j (coalesced 504B rows), unroll-2.
    uint64_t o = 0;
    {
        int l = wave;
        for (; l + 4 < n1; l += 8) {
            uint64_t a0 = (lane < NW) ? A[(size_t)list1[l] * NW + lane] : 0ull;
            uint64_t a1 = (lane < NW) ? A[(size_t)list1[l + 4] * NW + lane] : 0ull;
            o |= a0 | a1;
        }
        if (l < n1) o |= (lane < NW) ? A[(size_t)list1[l] * NW + lane] : 0ull;
    }
    m2part[wave][lane] = o;
    __syncthreads();

    // wave 0: OR-combine, shfl-scan, deterministic enumerate of M2(i)
    if (tid < 64) {
        uint64_t m = m2part[0][tid] | m2part[1][tid] | m2part[2][tid] | m2part[3][tid];
        m2row[tid] = m;
        int c = __popcll(m);
        int incl = wave64_incl_scan(c, tid);
        int oo = incl - c;
        int base = tid * 64;
        while (m) {
            int b = __builtin_ctzll(m);
            if (oo < MAXJ) list2[oo] = base + b;
            ++oo;
            m &= m - 1;
        }
        if (tid == 63) snn2 = incl < MAXJ ? incl : MAXJ;
    }
    __syncthreads();
    int n2 = snn2;

    // fused counts + weighted sum: wave per j, unroll-4 (8 loads in flight).
    const float2* fv1v = (const float2*)fv1;     // row = 64 float2
    float2 acc = {0.f, 0.f};
    {
        int l = wave;
        for (; l + 12 < n2; l += 16) {
            int j0 = list2[l];                   // LDS broadcast
            int j1 = list2[l + 4];
            int j2 = list2[l + 8];
            int j3 = list2[l + 12];
            int u0 = nbr[(size_t)j0 * CAP + lane];       // coalesced 256B each
            int u1 = nbr[(size_t)j1 * CAP + lane];
            int u2 = nbr[(size_t)j2 * CAP + lane];
            int u3 = nbr[(size_t)j3 * CAP + lane];
            float2 r0 = fv1v[(size_t)j0 * 64 + lane];    // coalesced 512B each
            float2 r1 = fv1v[(size_t)j1 * 64 + lane];
            float2 r2 = fv1v[(size_t)j2 * 64 + lane];
            float2 r3 = fv1v[(size_t)j3 * 64 + lane];
            bool p0 = (m2row[u0 >> 6] >> (u0 & 63)) & 1ull;
            bool p1 = (m2row[u1 >> 6] >> (u1 & 63)) & 1ull;
            bool p2 = (m2row[u2 >> 6] >> (u2 & 63)) & 1ull;
            bool p3 = (m2row[u3 >> 6] >> (u3 & 63)) & 1ull;
            float c0 = (float)__popcll(__ballot(p0));    // exact small ints
            float c1 = (float)__popcll(__ballot(p1));
            float c2 = (float)__popcll(__ballot(p2));
            float c3 = (float)__popcll(__ballot(p3));
            acc.x = fmaf(c0, r0.x, acc.x); acc.y = fmaf(c0, r0.y, acc.y);
            acc.x = fmaf(c1, r1.x, acc.x); acc.y = fmaf(c1, r1.y, acc.y);
            acc.x = fmaf(c2, r2.x, acc.x); acc.y = fmaf(c2, r2.y, acc.y);
            acc.x = fmaf(c3, r3.x, acc.x); acc.y = fmaf(c3, r3.y, acc.y);
        }
        for (; l < n2; l += 4) {
            int j0 = list2[l];
            int u0 = nbr[(size_t)j0 * CAP + lane];
            float2 r0 = fv1v[(size_t)j0 * 64 + lane];
            bool p0 = (m2row[u0 >> 6] >> (u0 & 63)) & 1ull;
            float c0 = (float)__popcll(__ballot(p0));
            acc.x = fmaf(c0, r0.x, acc.x); acc.y = fmaf(c0, r0.y, acc.y);
        }
    }
    if (wave > 0) wacc[wave - 1][lane] = acc;
    __syncthreads();
    if (wave == 0) {
        float2 s0 = wacc[0][lane], s1 = wacc[1][lane], s2 = wacc[2][lane];
        float2 s = { acc.x + s0.x + s1.x + s2.x, acc.y + s0.y + s1.y + s2.y };
        ((float2*)out)[(size_t)i * 64 + lane] = s;   // coalesced 512B
    }
}

extern "C" void kernel_launch(void* const* d_in, const int* in_sizes, int n_in,
                              void* d_out, int out_size, void* d_ws, size_t ws_size,
                              hipStream_t stream) {
    const float* node_loc = (const float*)d_in[0];  // [4000,2]
    const float* td       = (const float*)d_in[1];  // [4000,1]
    const float* depot    = (const float*)d_in[2];  // [1,2]
    const float* W0w      = (const float*)d_in[3];  // [128,3]
    const float* W0b      = (const float*)d_in[4];  // [128]
    float* out = (float*)d_out;                     // [4001,128]

    char* base = (char*)d_ws;
    size_t off = 0;
    auto carve = [&](size_t bytes) {
        char* p = base + off;
        off = (off + bytes + 511) & ~(size_t)511;
        return p;
    };
    uint64_t* A   = (uint64_t*)carve((size_t)M_NODES * NW * sizeof(uint64_t));  // ~2.0 MB
    float*    fv0 = (float*)   carve((size_t)M_NODES * DIM * sizeof(float));    // ~2.0 MB
    float*    fv1 = (float*)   carve((size_t)M_NODES * DIM * sizeof(float));    // ~2.0 MB
    int*      nbr = (int*)     carve((size_t)M_NODES * CAP * sizeof(int));      // ~1.5 MB
    int*      deg = (int*)     carve((size_t)M_NODES * sizeof(int));            // 16 KB

    prep_kernel<<<ADJ_BLOCKS + FV0_BLOCKS, 256, 0, stream>>>(node_loc, td, depot,
                                                             W0w, W0b, A, fv0);
    fv1csr_kernel<<<M_NODES, 256, 0, stream>>>(A, fv0, nbr, deg, fv1);
    fv2_kernel<<<M_NODES, 256, 0, stream>>>(A, nbr, deg, fv1, out);
}